// Round 4
// baseline (242.672 us; speedup 1.0000x reference)
//
#include <hip/hip_runtime.h>
#include <hip/hip_bf16.h>

#define BATCH 2
#define NQ 8192
#define NTOK 21760

typedef __attribute__((ext_vector_type(4))) float f32x4;
typedef __attribute__((ext_vector_type(8))) short s16x8;
typedef __attribute__((ext_vector_type(4))) _Float16 f16x4;

static __device__ __forceinline__ unsigned short f2bu(float x) {
    __hip_bfloat16 h = __float2bfloat16(x);
    return __builtin_bit_cast(unsigned short, h);
}

// ---------------- prep: transpose Wv/Wo -> bf16, Wqa = bf16(Wq@Wa)^T, bqa ----------------
// blocks 0..127: transpose; blocks 128..383: wqa rows.
__global__ __launch_bounds__(256) void prep_kernel(
    const float* __restrict__ Wq, const float* __restrict__ Wa,
    const float* __restrict__ bq, const float* __restrict__ ba,
    const float* __restrict__ Wv, const float* __restrict__ Wo,
    unsigned short* __restrict__ WqaT, float* __restrict__ bqa,
    unsigned short* __restrict__ WvT, unsigned short* __restrict__ WoT) {
    const int bid = blockIdx.x;
    const int tid = threadIdx.x;
    if (bid < 128) {
        __shared__ float t[32][33];
        const int mat = bid >> 6;
        const int tile = bid & 63;
        const int i0 = (tile >> 3) * 32, j0 = (tile & 7) * 32;
        const float* src = mat ? Wo : Wv;
        unsigned short* dst = mat ? WoT : WvT;
        const int tx = tid & 31, ty = tid >> 5;
#pragma unroll
        for (int r = 0; r < 4; ++r)
            t[ty + 8 * r][tx] = src[(i0 + ty + 8 * r) * 256 + j0 + tx];
        __syncthreads();
#pragma unroll
        for (int r = 0; r < 4; ++r)
            dst[(j0 + ty + 8 * r) * 256 + i0 + tx] = f2bu(t[tx][ty + 8 * r]);
    } else {
        __shared__ float red[256];
        const int i = bid - 128;          // 0..255
        const int j = tid & 127, kh = tid >> 7;
        float acc = 0.f;
#pragma unroll 8
        for (int k = kh * 128; k < kh * 128 + 128; ++k)
            acc += Wq[i * 256 + k] * Wa[k * 128 + j];
        red[tid] = acc;
        __syncthreads();
        if (kh == 0) {
            WqaT[j * 256 + i] = f2bu(red[j] + red[j + 128]);
            if (i == 0) {
                float b = ba[j];
#pragma unroll 8
                for (int k = 0; k < 256; ++k) b += bq[k] * Wa[k * 128 + j];
                bqa[j] = b;
            }
        }
    }
}

// ---------------- fused v-GEMM + logits-GEMM (both A fp32, K=256, 128x128 tiles) ----------------
// blocks 0..679: v = inflat @ WvT^T + bv -> bf16 [43520][256]
// blocks 680..807: logits = query @ WqaT^T + bqa -> fp32 [16384][128]
__global__ __launch_bounds__(256) void gemm_vlog(
    const float* __restrict__ inflat, const unsigned short* __restrict__ WvT,
    const float* __restrict__ bv, unsigned short* __restrict__ vbuf,
    const float* __restrict__ query, const unsigned short* __restrict__ WqaT,
    const float* __restrict__ bqa, float* __restrict__ logits) {
    constexpr int K = 256, NT = 4, RA = 4, RB = 4, IM = 4, JN = 4;
    __shared__ __align__(16) char As[128 * 128];
    __shared__ __align__(16) char Bs[128 * 128];
    const int bid = blockIdx.x;
    const float* A;
    const unsigned short* Bt;
    const float* bias;
    int bm, bn, N;
    bool b16;
    if (bid < 680) {
        A = inflat; Bt = WvT; bias = bv;
        bm = (bid >> 1) * 128; bn = (bid & 1) * 128; N = 256; b16 = true;
    } else {
        A = query; Bt = WqaT; bias = bqa;
        bm = (bid - 680) * 128; bn = 0; N = 128; b16 = false;
    }
    const int tid = threadIdx.x;
    const int lane = tid & 63;
    const int wave = tid >> 6;
    const int wr = wave >> 1, wc = wave & 1;
    const int srow = tid >> 3;
    const int skc = (tid & 7) * 8;

    f32x4 acc[IM][JN] = {};
    float4 af0[2][RA], af1[2][RA];
    s16x8 bb[2][RB];

    auto loadT = [&](int t, int buf) {
        const int k0 = t * 64;
#pragma unroll
        for (int r = 0; r < RA; ++r) {
            const float* Af = A + (size_t)(bm + srow + r * 32) * K + k0 + skc;
            af0[buf][r] = *(const float4*)Af;
            af1[buf][r] = *(const float4*)(Af + 4);
        }
#pragma unroll
        for (int r = 0; r < RB; ++r)
            bb[buf][r] = *(const s16x8*)(Bt + (size_t)(bn + srow + r * 32) * K + k0 + skc);
    };
    auto writeT = [&](int buf) {
#pragma unroll
        for (int r = 0; r < RA; ++r) {
            const int row = srow + r * 32;
            const int byte = (row * 128 + skc * 2) ^ ((row & 7) << 4);
            const float4 f0 = af0[buf][r], f1 = af1[buf][r];
            s16x8 av;
            av[0] = (short)f2bu(f0.x); av[1] = (short)f2bu(f0.y);
            av[2] = (short)f2bu(f0.z); av[3] = (short)f2bu(f0.w);
            av[4] = (short)f2bu(f1.x); av[5] = (short)f2bu(f1.y);
            av[6] = (short)f2bu(f1.z); av[7] = (short)f2bu(f1.w);
            *(s16x8*)(As + byte) = av;
        }
#pragma unroll
        for (int r = 0; r < RB; ++r) {
            const int row = srow + r * 32;
            const int byte = (row * 128 + skc * 2) ^ ((row & 7) << 4);
            *(s16x8*)(Bs + byte) = bb[buf][r];
        }
    };

    loadT(0, 0);
#pragma unroll
    for (int t = 0; t < NT; ++t) {
        if (t) __syncthreads();
        if (t + 1 < NT) loadT(t + 1, (t + 1) & 1);
        writeT(t & 1);
        __syncthreads();
#pragma unroll
        for (int f = 0; f < 2; ++f) {
            s16x8 a[IM], b[JN];
#pragma unroll
            for (int i = 0; i < IM; ++i) {
                const int arow = wr * 64 + i * 16 + (lane & 15);
                const int abyte = (arow * 128 + f * 64 + (lane >> 4) * 16) ^ ((arow & 7) << 4);
                a[i] = *(const s16x8*)(As + abyte);
            }
#pragma unroll
            for (int j = 0; j < JN; ++j) {
                const int brow = wc * 64 + j * 16 + (lane & 15);
                const int bbyte = (brow * 128 + f * 64 + (lane >> 4) * 16) ^ ((brow & 7) << 4);
                b[j] = *(const s16x8*)(Bs + bbyte);
            }
#pragma unroll
            for (int i = 0; i < IM; ++i)
#pragma unroll
                for (int j = 0; j < JN; ++j)
                    acc[i][j] = __builtin_amdgcn_mfma_f32_16x16x32_bf16(a[i], b[j], acc[i][j], 0, 0, 0);
        }
    }

#pragma unroll
    for (int i = 0; i < IM; ++i) {
        const int row0 = bm + wr * 64 + i * 16 + (lane >> 4) * 4;
#pragma unroll
        for (int j = 0; j < JN; ++j) {
            const int col = bn + wc * 64 + j * 16 + (lane & 15);
            const float bsv = bias[col];
#pragma unroll
            for (int q = 0; q < 4; ++q) {
                const float val = acc[i][j][q] + bsv;
                if (b16) vbuf[(size_t)(row0 + q) * N + col] = f2bu(val);
                else logits[(size_t)(row0 + q) * N + col] = val;
            }
        }
    }
}

// ---------------- MFMA bf16 GEMM (A bf16): out = samp @ WoT^T + bo ----------------
template <int BM, int BN, int WRN, int WCN>
__global__ __launch_bounds__(256) void gemm_out(
    const unsigned short* __restrict__ Av, const unsigned short* __restrict__ Bt,
    const float* __restrict__ bias, float* __restrict__ Cv, int N) {
    constexpr int K = 256, NT = 4;
    constexpr int IM = BM / (WRN * 16);
    constexpr int JN = BN / (WCN * 16);
    constexpr int RA = BM / 32;
    constexpr int RB = BN / 32;
    __shared__ __align__(16) char As[BM * 128];
    __shared__ __align__(16) char Bs[BN * 128];
    const int tid = threadIdx.x;
    const int lane = tid & 63;
    const int wave = tid >> 6;
    const int wr = wave / WCN, wc = wave % WCN;
    const int bm = blockIdx.y * BM, bn = blockIdx.x * BN;
    const int srow = tid >> 3;
    const int skc = (tid & 7) * 8;

    f32x4 acc[IM][JN] = {};
    s16x8 ab[2][RA], bb[2][RB];

    auto loadT = [&](int t, int buf) {
        const int k0 = t * 64;
#pragma unroll
        for (int r = 0; r < RA; ++r)
            ab[buf][r] = *(const s16x8*)(Av + (size_t)(bm + srow + r * 32) * K + k0 + skc);
#pragma unroll
        for (int r = 0; r < RB; ++r)
            bb[buf][r] = *(const s16x8*)(Bt + (size_t)(bn + srow + r * 32) * K + k0 + skc);
    };
    auto writeT = [&](int buf) {
#pragma unroll
        for (int r = 0; r < RA; ++r) {
            const int row = srow + r * 32;
            *(s16x8*)(As + ((row * 128 + skc * 2) ^ ((row & 7) << 4))) = ab[buf][r];
        }
#pragma unroll
        for (int r = 0; r < RB; ++r) {
            const int row = srow + r * 32;
            *(s16x8*)(Bs + ((row * 128 + skc * 2) ^ ((row & 7) << 4))) = bb[buf][r];
        }
    };

    loadT(0, 0);
#pragma unroll
    for (int t = 0; t < NT; ++t) {
        if (t) __syncthreads();
        if (t + 1 < NT) loadT(t + 1, (t + 1) & 1);
        writeT(t & 1);
        __syncthreads();
#pragma unroll
        for (int f = 0; f < 2; ++f) {
            s16x8 a[IM], b[JN];
#pragma unroll
            for (int i = 0; i < IM; ++i) {
                const int arow = wr * (IM * 16) + i * 16 + (lane & 15);
                a[i] = *(const s16x8*)(As + ((arow * 128 + f * 64 + (lane >> 4) * 16) ^ ((arow & 7) << 4)));
            }
#pragma unroll
            for (int j = 0; j < JN; ++j) {
                const int brow = wc * (JN * 16) + j * 16 + (lane & 15);
                b[j] = *(const s16x8*)(Bs + ((brow * 128 + f * 64 + (lane >> 4) * 16) ^ ((brow & 7) << 4)));
            }
#pragma unroll
            for (int i = 0; i < IM; ++i)
#pragma unroll
                for (int j = 0; j < JN; ++j)
                    acc[i][j] = __builtin_amdgcn_mfma_f32_16x16x32_bf16(a[i], b[j], acc[i][j], 0, 0, 0);
        }
    }

#pragma unroll
    for (int i = 0; i < IM; ++i) {
        const int row0 = bm + wr * (IM * 16) + i * 16 + (lane >> 4) * 4;
#pragma unroll
        for (int j = 0; j < JN; ++j) {
            const int col = bn + wc * (JN * 16) + j * 16 + (lane & 15);
            const float bsv = bias[col];
#pragma unroll
            for (int q = 0; q < 4; ++q)
                Cv[(size_t)(row0 + q) * N + col] = acc[i][j][q] + bsv;
        }
    }
}

// ---------------- sample: fused softmax + bilinear gather, pipelined ----------------
// Block = 4 queries, 128 threads. Phase 1: 512 point-slots (4 rounds) -> meta in LDS.
// Phase 2: 128 threads = 4q x 8h x 4c, 8 channels/lane via dwordx4, 2-stage pipeline.
__global__ __launch_bounds__(128) void sample_kernel(
    const float* __restrict__ refp, const float* __restrict__ sloc,
    const unsigned int* __restrict__ v,      // bf16 pairs [B][NTOK][128]
    const float* __restrict__ logits,        // [B*NQ][128]
    unsigned int* __restrict__ samp) {       // bf16 pairs [B*NQ][128]
    const int tid = threadIdx.x;
    const int q0 = blockIdx.x * 4;
    __shared__ int4 mI[528];      // idx = s + (s>>5), s = lp*32 + qi*8 + h
    __shared__ f16x4 mW[528];
    __shared__ float slc[256];
    __shared__ float lgs[512];
    __shared__ float rps[32];

#pragma unroll
    for (int r = 0; r < 2; ++r) {
        const int t = tid + 128 * r;
        const int l = (t >> 3) & 3;
        slc[t] = sloc[t] * (float)(128 >> l) - 0.5f;
    }
#pragma unroll
    for (int r = 0; r < 4; ++r)
        lgs[tid + 128 * r] = logits[(size_t)q0 * 128 + tid + 128 * r];
    if (tid < 32) rps[tid] = refp[(size_t)q0 * 8 + tid];
    __syncthreads();

#pragma unroll
    for (int ss = 0; ss < 4; ++ss) {
        const int h = tid & 7;
        const int p = (tid >> 3) & 3;
        const int l = tid >> 5;
        const int qi = ss;
        const int lp = l * 4 + p;
        const int b = (q0 + qi) >> 13;  // NQ=8192
        const int Wl = 128 >> l;
        const float lg = lgs[qi * 128 + h * 16 + lp];
        float m = fmaxf(lg, __shfl_xor(lg, 8));
        m = fmaxf(m, __shfl_xor(m, 16));
        const float e = __expf(lg - m);
        float sum = e + __shfl_xor(e, 8);
        sum += __shfl_xor(sum, 16);
        const float a = e / sum;
        const float fW = (float)Wl;
        const float ix = fmaf(rps[qi * 8 + l * 2 + 0], fW, slc[h * 32 + l * 8 + p * 2 + 0]);
        const float iy = fmaf(rps[qi * 8 + l * 2 + 1], fW, slc[h * 32 + l * 8 + p * 2 + 1]);
        const float xf = floorf(ix), yf = floorf(iy);
        const int x0 = (int)xf, y0 = (int)yf;
        const int x1 = x0 + 1, y1 = y0 + 1;
        float wx1 = ix - xf, wy1 = iy - yf;
        float wx0 = 1.f - wx1, wy0 = 1.f - wy1;
        wx0 = ((unsigned)x0 < (unsigned)Wl) ? wx0 : 0.f;
        wx1 = ((unsigned)x1 < (unsigned)Wl) ? wx1 : 0.f;
        wy0 = ((unsigned)y0 < (unsigned)Wl) ? wy0 * a : 0.f;
        wy1 = ((unsigned)y1 < (unsigned)Wl) ? wy1 * a : 0.f;
        const int x0c = min(max(x0, 0), Wl - 1);
        const int x1c = min(max(x1, 0), Wl - 1);
        const int y0c = min(max(y0, 0), Wl - 1);
        const int y1c = min(max(y1, 0), Wl - 1);
        const int SS = (65536 - (65536 >> (2 * l))) / 3;
        const int base = b * (NTOK * 128) + SS * 128 + h * 16;
        const int r0 = y0c * Wl, r1 = y1c * Wl;
        const int s = lp * 32 + qi * 8 + h;
        const int ixd = s + lp;
        mI[ixd] = make_int4(base + (r0 + x0c) * 128, base + (r0 + x1c) * 128,
                            base + (r1 + x0c) * 128, base + (r1 + x1c) * 128);
        mW[ixd] = (f16x4){(_Float16)(wy0 * wx0), (_Float16)(wy0 * wx1),
                          (_Float16)(wy1 * wx0), (_Float16)(wy1 * wx1)};
    }
    __syncthreads();

    const int qi = tid >> 5, h = (tid >> 2) & 7, c = tid & 3;
    const int sbase = qi * 8 + h;
    float a0 = 0.f, a1 = 0.f, a2 = 0.f, a3 = 0.f;
    float a4 = 0.f, a5 = 0.f, a6 = 0.f, a7 = 0.f;

    auto fma4 = [&](const uint4& u, float w) {
        a0 = fmaf(__uint_as_float(u.x << 16), w, a0);
        a1 = fmaf(__uint_as_float(u.x), w, a1);          // hi bf16 + junk mantissa (<2^-7 rel)
        a2 = fmaf(__uint_as_float(u.y << 16), w, a2);
        a3 = fmaf(__uint_as_float(u.y), w, a3);
        a4 = fmaf(__uint_as_float(u.z << 16), w, a4);
        a5 = fmaf(__uint_as_float(u.z), w, a5);
        a6 = fmaf(__uint_as_float(u.w << 16), w, a6);
        a7 = fmaf(__uint_as_float(u.w), w, a7);
    };

    int4 I = mI[sbase];
    f16x4 Wh = mW[sbase];
    uint4 u0 = *((const uint4*)(v + I.x) + c);
    uint4 u1 = *((const uint4*)(v + I.y) + c);
    uint4 u2 = *((const uint4*)(v + I.z) + c);
    uint4 u3 = *((const uint4*)(v + I.w) + c);
#pragma unroll
    for (int lp = 0; lp < 16; ++lp) {
        int4 In;
        f16x4 Wn;
        uint4 n0, n1, n2, n3;
        if (lp < 15) {
            const int s = (lp + 1) * 32 + sbase;
            In = mI[s + lp + 1];
            Wn = mW[s + lp + 1];
            n0 = *((const uint4*)(v + In.x) + c);
            n1 = *((const uint4*)(v + In.y) + c);
            n2 = *((const uint4*)(v + In.z) + c);
            n3 = *((const uint4*)(v + In.w) + c);
        }
        fma4(u0, (float)Wh[0]);
        fma4(u1, (float)Wh[1]);
        fma4(u2, (float)Wh[2]);
        fma4(u3, (float)Wh[3]);
        if (lp < 15) { I = In; Wh = Wn; u0 = n0; u1 = n1; u2 = n2; u3 = n3; }
    }
    uint4 o;
    o.x = (unsigned)f2bu(a0) | ((unsigned)f2bu(a1) << 16);
    o.y = (unsigned)f2bu(a2) | ((unsigned)f2bu(a3) << 16);
    o.z = (unsigned)f2bu(a4) | ((unsigned)f2bu(a5) << 16);
    o.w = (unsigned)f2bu(a6) | ((unsigned)f2bu(a7) << 16);
    *(uint4*)(samp + (size_t)(q0 + qi) * 128 + h * 16 + c * 4) = o;
}

extern "C" void kernel_launch(void* const* d_in, const int* in_sizes, int n_in,
                              void* d_out, int out_size, void* d_ws, size_t ws_size,
                              hipStream_t stream) {
    const float* query  = (const float*)d_in[0];
    const float* refp   = (const float*)d_in[1];
    const float* inflat = (const float*)d_in[2];
    const float* Wq = (const float*)d_in[5];
    const float* bq = (const float*)d_in[6];
    const float* Wv = (const float*)d_in[7];
    const float* bv = (const float*)d_in[8];
    const float* Wa = (const float*)d_in[9];
    const float* ba = (const float*)d_in[10];
    const float* sloc = (const float*)d_in[11];
    const float* Wo = (const float*)d_in[12];
    const float* bo = (const float*)d_in[13];
    float* out = (float*)d_out;

    char* ws = (char*)d_ws;
    unsigned short* WqaT = (unsigned short*)(ws + 0);            // 64 KB  [128][256] bf16
    float* bqa = (float*)(ws + (64u << 10));                     // 512 B
    unsigned short* WvT = (unsigned short*)(ws + (128u << 10));  // 128 KB [256][256] bf16
    unsigned short* WoT = (unsigned short*)(ws + (256u << 10));  // 128 KB
    unsigned short* vbuf = (unsigned short*)(ws + (1u << 20));   // 22.3 MB bf16 [B][NTOK][256]
    float* logits = (float*)(ws + (24u << 20));                  // 8 MB fp32 [B*NQ][128]
    unsigned int* samp = (unsigned int*)(ws + (32u << 20));      // 8 MB bf16 [B*NQ][256]

    prep_kernel<<<384, 256, 0, stream>>>(Wq, Wa, bq, ba, Wv, Wo, WqaT, bqa, WvT, WoT);
    gemm_vlog<<<808, 256, 0, stream>>>(inflat, WvT, bv, vbuf, query, WqaT, bqa, logits);
    sample_kernel<<<BATCH * NQ / 4, 128, 0, stream>>>(refp, sloc, (const unsigned int*)vbuf, logits, samp);
    gemm_out<64, 128, 1, 4><<<dim3(2, 256), 256, 0, stream>>>((const unsigned short*)samp, WoT, bo, out, 256);
}

// Round 7
// 204.643 us; speedup vs baseline: 1.1858x; 1.1858x over previous
//
#include <hip/hip_runtime.h>
#include <hip/hip_bf16.h>

#define BATCH 2
#define NQ 8192
#define NTOK 21760

typedef __attribute__((ext_vector_type(4))) float f32x4;
typedef __attribute__((ext_vector_type(8))) short s16x8;

static __device__ __forceinline__ unsigned short f2bu(float x) {
    __hip_bfloat16 h = __float2bfloat16(x);
    return __builtin_bit_cast(unsigned short, h);
}

// ---------------- prep: transpose Wv/Wo -> bf16, Wqa = bf16(Wq@Wa)^T, bqa ----------------
__global__ __launch_bounds__(256) void prep_kernel(
    const float* __restrict__ Wq, const float* __restrict__ Wa,
    const float* __restrict__ bq, const float* __restrict__ ba,
    const float* __restrict__ Wv, const float* __restrict__ Wo,
    unsigned short* __restrict__ WqaT, float* __restrict__ bqa,
    unsigned short* __restrict__ WvT, unsigned short* __restrict__ WoT) {
    const int bid = blockIdx.x;
    const int tid = threadIdx.x;
    if (bid < 128) {
        __shared__ float t[32][33];
        const int mat = bid >> 6;
        const int tile = bid & 63;
        const int i0 = (tile >> 3) * 32, j0 = (tile & 7) * 32;
        const float* src = mat ? Wo : Wv;
        unsigned short* dst = mat ? WoT : WvT;
        const int tx = tid & 31, ty = tid >> 5;
#pragma unroll
        for (int r = 0; r < 4; ++r)
            t[ty + 8 * r][tx] = src[(i0 + ty + 8 * r) * 256 + j0 + tx];
        __syncthreads();
#pragma unroll
        for (int r = 0; r < 4; ++r)
            dst[(j0 + ty + 8 * r) * 256 + i0 + tx] = f2bu(t[tx][ty + 8 * r]);
    } else {
        __shared__ float red[256];
        const int i = bid - 128;
        const int j = tid & 127, kh = tid >> 7;
        float acc = 0.f;
#pragma unroll 8
        for (int k = kh * 128; k < kh * 128 + 128; ++k)
            acc += Wq[i * 256 + k] * Wa[k * 128 + j];
        red[tid] = acc;
        __syncthreads();
        if (kh == 0) {
            WqaT[j * 256 + i] = f2bu(red[j] + red[j + 128]);
            if (i == 0) {
                float b = ba[j];
#pragma unroll 8
                for (int k = 0; k < 256; ++k) b += bq[k] * Wa[k * 128 + j];
                bqa[j] = b;
            }
        }
    }
}

// ---------------- fused v-GEMM + logits-GEMM (both A fp32, K=256, 128x128 tiles) ----------------
__global__ __launch_bounds__(256) void gemm_vlog(
    const float* __restrict__ inflat, const unsigned short* __restrict__ WvT,
    const float* __restrict__ bv, unsigned short* __restrict__ vbuf,
    const float* __restrict__ query, const unsigned short* __restrict__ WqaT,
    const float* __restrict__ bqa, float* __restrict__ logits) {
    constexpr int K = 256, NT = 4, RA = 4, RB = 4, IM = 4, JN = 4;
    __shared__ __align__(16) char As[128 * 128];
    __shared__ __align__(16) char Bs[128 * 128];
    const int bid = blockIdx.x;
    const float* A;
    const unsigned short* Bt;
    const float* bias;
    int bm, bn, N;
    bool b16;
    if (bid < 680) {
        A = inflat; Bt = WvT; bias = bv;
        bm = (bid >> 1) * 128; bn = (bid & 1) * 128; N = 256; b16 = true;
    } else {
        A = query; Bt = WqaT; bias = bqa;
        bm = (bid - 680) * 128; bn = 0; N = 128; b16 = false;
    }
    const int tid = threadIdx.x;
    const int lane = tid & 63;
    const int wave = tid >> 6;
    const int wr = wave >> 1, wc = wave & 1;
    const int srow = tid >> 3;
    const int skc = (tid & 7) * 8;

    f32x4 acc[IM][JN] = {};
    float4 af0[2][RA], af1[2][RA];
    s16x8 bb[2][RB];

    auto loadT = [&](int t, int buf) {
        const int k0 = t * 64;
#pragma unroll
        for (int r = 0; r < RA; ++r) {
            const float* Af = A + (size_t)(bm + srow + r * 32) * K + k0 + skc;
            af0[buf][r] = *(const float4*)Af;
            af1[buf][r] = *(const float4*)(Af + 4);
        }
#pragma unroll
        for (int r = 0; r < RB; ++r)
            bb[buf][r] = *(const s16x8*)(Bt + (size_t)(bn + srow + r * 32) * K + k0 + skc);
    };
    auto writeT = [&](int buf) {
#pragma unroll
        for (int r = 0; r < RA; ++r) {
            const int row = srow + r * 32;
            const int byte = (row * 128 + skc * 2) ^ ((row & 7) << 4);
            const float4 f0 = af0[buf][r], f1 = af1[buf][r];
            s16x8 av;
            av[0] = (short)f2bu(f0.x); av[1] = (short)f2bu(f0.y);
            av[2] = (short)f2bu(f0.z); av[3] = (short)f2bu(f0.w);
            av[4] = (short)f2bu(f1.x); av[5] = (short)f2bu(f1.y);
            av[6] = (short)f2bu(f1.z); av[7] = (short)f2bu(f1.w);
            *(s16x8*)(As + byte) = av;
        }
#pragma unroll
        for (int r = 0; r < RB; ++r) {
            const int row = srow + r * 32;
            const int byte = (row * 128 + skc * 2) ^ ((row & 7) << 4);
            *(s16x8*)(Bs + byte) = bb[buf][r];
        }
    };

    loadT(0, 0);
#pragma unroll
    for (int t = 0; t < NT; ++t) {
        if (t) __syncthreads();
        if (t + 1 < NT) loadT(t + 1, (t + 1) & 1);
        writeT(t & 1);
        __syncthreads();
#pragma unroll
        for (int f = 0; f < 2; ++f) {
            s16x8 a[IM], b[JN];
#pragma unroll
            for (int i = 0; i < IM; ++i) {
                const int arow = wr * 64 + i * 16 + (lane & 15);
                const int abyte = (arow * 128 + f * 64 + (lane >> 4) * 16) ^ ((arow & 7) << 4);
                a[i] = *(const s16x8*)(As + abyte);
            }
#pragma unroll
            for (int j = 0; j < JN; ++j) {
                const int brow = wc * 64 + j * 16 + (lane & 15);
                const int bbyte = (brow * 128 + f * 64 + (lane >> 4) * 16) ^ ((brow & 7) << 4);
                b[j] = *(const s16x8*)(Bs + bbyte);
            }
#pragma unroll
            for (int i = 0; i < IM; ++i)
#pragma unroll
                for (int j = 0; j < JN; ++j)
                    acc[i][j] = __builtin_amdgcn_mfma_f32_16x16x32_bf16(a[i], b[j], acc[i][j], 0, 0, 0);
        }
    }

#pragma unroll
    for (int i = 0; i < IM; ++i) {
        const int row0 = bm + wr * 64 + i * 16 + (lane >> 4) * 4;
#pragma unroll
        for (int j = 0; j < JN; ++j) {
            const int col = bn + wc * 64 + j * 16 + (lane & 15);
            const float bsv = bias[col];
#pragma unroll
            for (int q = 0; q < 4; ++q) {
                const float val = acc[i][j][q] + bsv;
                if (b16) vbuf[(size_t)(row0 + q) * N + col] = f2bu(val);
                else logits[(size_t)(row0 + q) * N + col] = val;
            }
        }
    }
}

// ---------------- MFMA bf16 GEMM (A bf16): out = samp @ WoT^T + bo ----------------
template <int BM, int BN, int WRN, int WCN>
__global__ __launch_bounds__(256) void gemm_out(
    const unsigned short* __restrict__ Av, const unsigned short* __restrict__ Bt,
    const float* __restrict__ bias, float* __restrict__ Cv, int N) {
    constexpr int K = 256, NT = 4;
    constexpr int IM = BM / (WRN * 16);
    constexpr int JN = BN / (WCN * 16);
    constexpr int RA = BM / 32;
    constexpr int RB = BN / 32;
    __shared__ __align__(16) char As[BM * 128];
    __shared__ __align__(16) char Bs[BN * 128];
    const int tid = threadIdx.x;
    const int lane = tid & 63;
    const int wave = tid >> 6;
    const int wr = wave / WCN, wc = wave % WCN;
    const int bm = blockIdx.y * BM, bn = blockIdx.x * BN;
    const int srow = tid >> 3;
    const int skc = (tid & 7) * 8;

    f32x4 acc[IM][JN] = {};
    s16x8 ab[2][RA], bb[2][RB];

    auto loadT = [&](int t, int buf) {
        const int k0 = t * 64;
#pragma unroll
        for (int r = 0; r < RA; ++r)
            ab[buf][r] = *(const s16x8*)(Av + (size_t)(bm + srow + r * 32) * K + k0 + skc);
#pragma unroll
        for (int r = 0; r < RB; ++r)
            bb[buf][r] = *(const s16x8*)(Bt + (size_t)(bn + srow + r * 32) * K + k0 + skc);
    };
    auto writeT = [&](int buf) {
#pragma unroll
        for (int r = 0; r < RA; ++r) {
            const int row = srow + r * 32;
            *(s16x8*)(As + ((row * 128 + skc * 2) ^ ((row & 7) << 4))) = ab[buf][r];
        }
#pragma unroll
        for (int r = 0; r < RB; ++r) {
            const int row = srow + r * 32;
            *(s16x8*)(Bs + ((row * 128 + skc * 2) ^ ((row & 7) << 4))) = bb[buf][r];
        }
    };

    loadT(0, 0);
#pragma unroll
    for (int t = 0; t < NT; ++t) {
        if (t) __syncthreads();
        if (t + 1 < NT) loadT(t + 1, (t + 1) & 1);
        writeT(t & 1);
        __syncthreads();
#pragma unroll
        for (int f = 0; f < 2; ++f) {
            s16x8 a[IM], b[JN];
#pragma unroll
            for (int i = 0; i < IM; ++i) {
                const int arow = wr * (IM * 16) + i * 16 + (lane & 15);
                a[i] = *(const s16x8*)(As + ((arow * 128 + f * 64 + (lane >> 4) * 16) ^ ((arow & 7) << 4)));
            }
#pragma unroll
            for (int j = 0; j < JN; ++j) {
                const int brow = wc * (JN * 16) + j * 16 + (lane & 15);
                b[j] = *(const s16x8*)(Bs + ((brow * 128 + f * 64 + (lane >> 4) * 16) ^ ((brow & 7) << 4)));
            }
#pragma unroll
            for (int i = 0; i < IM; ++i)
#pragma unroll
                for (int j = 0; j < JN; ++j)
                    acc[i][j] = __builtin_amdgcn_mfma_f32_16x16x32_bf16(a[i], b[j], acc[i][j], 0, 0, 0);
        }
    }

#pragma unroll
    for (int i = 0; i < IM; ++i) {
        const int row0 = bm + wr * (IM * 16) + i * 16 + (lane >> 4) * 4;
#pragma unroll
        for (int j = 0; j < JN; ++j) {
            const int col = bn + wc * (JN * 16) + j * 16 + (lane & 15);
            const float bsv = bias[col];
#pragma unroll
            for (int q = 0; q < 4; ++q)
                Cv[(size_t)(row0 + q) * N + col] = acc[i][j][q] + bsv;
        }
    }
}

// ---------------- sample: fused softmax + bilinear gather, 2-stage ping-pong ----------------
// Block = 4 queries, 256 threads. Phase 1: 512 point-slots (2 rounds) -> meta in LDS.
// Phase 2: 1 wave per query (8h x 8c), uint2 (4ch)/lane, next point's loads in flight.
__global__ __launch_bounds__(256) void sample_kernel(
    const float* __restrict__ refp, const float* __restrict__ sloc,
    const unsigned int* __restrict__ v,      // bf16 pairs [B][NTOK][128]
    const float* __restrict__ logits,        // [B*NQ][128]
    unsigned int* __restrict__ samp) {       // bf16 pairs [B*NQ][128]
    const int tid = threadIdx.x;
    const int q0 = blockIdx.x * 4;
    __shared__ int4 mI[512];       // s = lp*32 + qi*8 + h
    __shared__ float4 mW[512];
    __shared__ float slc[256];
    __shared__ float lgs[512];
    __shared__ float rps[32];

    {
        const int l = (tid >> 3) & 3;  // sloc layout [h][l][p][c]
        slc[tid] = sloc[tid] * (float)(128 >> l) - 0.5f;
    }
    lgs[tid] = logits[(size_t)q0 * 128 + tid];
    lgs[tid + 256] = logits[(size_t)q0 * 128 + tid + 256];
    if (tid < 32) rps[tid] = refp[(size_t)q0 * 8 + tid];
    __syncthreads();

#pragma unroll
    for (int ss = 0; ss < 2; ++ss) {
        const int h = tid & 7;
        const int p = (tid >> 3) & 3;
        const int l = (tid >> 5) & 3;
        const int qi = (tid >> 7) + ss * 2;
        const int lp = l * 4 + p;
        const int b = (q0 + qi) >> 13;  // NQ=8192
        const int Wl = 128 >> l;
        // softmax over p (partners at lane^8, lane^16 share qi,h,l)
        const float lg = lgs[qi * 128 + h * 16 + lp];
        float m = fmaxf(lg, __shfl_xor(lg, 8));
        m = fmaxf(m, __shfl_xor(m, 16));
        const float e = __expf(lg - m);
        float sum = e + __shfl_xor(e, 8);
        sum += __shfl_xor(sum, 16);
        const float a = e / sum;
        const float fW = (float)Wl;
        const float ix = fmaf(rps[qi * 8 + l * 2 + 0], fW, slc[h * 32 + l * 8 + p * 2 + 0]);
        const float iy = fmaf(rps[qi * 8 + l * 2 + 1], fW, slc[h * 32 + l * 8 + p * 2 + 1]);
        const float xf = floorf(ix), yf = floorf(iy);
        const int x0 = (int)xf, y0 = (int)yf;
        const int x1 = x0 + 1, y1 = y0 + 1;
        float wx1 = ix - xf, wy1 = iy - yf;
        float wx0 = 1.f - wx1, wy0 = 1.f - wy1;
        wx0 = ((unsigned)x0 < (unsigned)Wl) ? wx0 : 0.f;
        wx1 = ((unsigned)x1 < (unsigned)Wl) ? wx1 : 0.f;
        wy0 = ((unsigned)y0 < (unsigned)Wl) ? wy0 * a : 0.f;
        wy1 = ((unsigned)y1 < (unsigned)Wl) ? wy1 * a : 0.f;
        const int x0c = min(max(x0, 0), Wl - 1);
        const int x1c = min(max(x1, 0), Wl - 1);
        const int y0c = min(max(y0, 0), Wl - 1);
        const int y1c = min(max(y1, 0), Wl - 1);
        const int SS = (65536 - (65536 >> (2 * l))) / 3;
        const int base = b * (NTOK * 128) + SS * 128 + h * 16;
        const int r0 = y0c * Wl, r1 = y1c * Wl;
        const int s = lp * 32 + qi * 8 + h;
        mI[s] = make_int4(base + (r0 + x0c) * 128, base + (r0 + x1c) * 128,
                          base + (r1 + x0c) * 128, base + (r1 + x1c) * 128);
        mW[s] = make_float4(wy0 * wx0, wy0 * wx1, wy1 * wx0, wy1 * wx1);
    }
    __syncthreads();

    const int qi = tid >> 6, h = (tid >> 3) & 7, c = tid & 7;
    const int sb = qi * 8 + h;
    const unsigned int* vp = v + c * 2;
    float a0 = 0.f, a1 = 0.f, a2 = 0.f, a3 = 0.f;

    int4 I[2];
    float4 W[2];
    uint2 u[2][4];
    I[0] = mI[sb];
    W[0] = mW[sb];
    u[0][0] = *(const uint2*)(vp + I[0].x);
    u[0][1] = *(const uint2*)(vp + I[0].y);
    u[0][2] = *(const uint2*)(vp + I[0].z);
    u[0][3] = *(const uint2*)(vp + I[0].w);
#pragma unroll
    for (int lp = 0; lp < 16; ++lp) {
        const int cur = lp & 1, nxt = cur ^ 1;
        if (lp < 15) {
            const int s = (lp + 1) * 32 + sb;
            I[nxt] = mI[s];
            W[nxt] = mW[s];
            u[nxt][0] = *(const uint2*)(vp + I[nxt].x);
            u[nxt][1] = *(const uint2*)(vp + I[nxt].y);
            u[nxt][2] = *(const uint2*)(vp + I[nxt].z);
            u[nxt][3] = *(const uint2*)(vp + I[nxt].w);
        }
        const float4 Wc = W[cur];
        // per corner: lo ch = <<16 exact; hi ch = raw dword (junk low mantissa < 2^-8 rel)
        a0 = fmaf(__uint_as_float(u[cur][0].x << 16), Wc.x, a0);
        a1 = fmaf(__uint_as_float(u[cur][0].x), Wc.x, a1);
        a2 = fmaf(__uint_as_float(u[cur][0].y << 16), Wc.x, a2);
        a3 = fmaf(__uint_as_float(u[cur][0].y), Wc.x, a3);
        a0 = fmaf(__uint_as_float(u[cur][1].x << 16), Wc.y, a0);
        a1 = fmaf(__uint_as_float(u[cur][1].x), Wc.y, a1);
        a2 = fmaf(__uint_as_float(u[cur][1].y << 16), Wc.y, a2);
        a3 = fmaf(__uint_as_float(u[cur][1].y), Wc.y, a3);
        a0 = fmaf(__uint_as_float(u[cur][2].x << 16), Wc.z, a0);
        a1 = fmaf(__uint_as_float(u[cur][2].x), Wc.z, a1);
        a2 = fmaf(__uint_as_float(u[cur][2].y << 16), Wc.z, a2);
        a3 = fmaf(__uint_as_float(u[cur][2].y), Wc.z, a3);
        a0 = fmaf(__uint_as_float(u[cur][3].x << 16), Wc.w, a0);
        a1 = fmaf(__uint_as_float(u[cur][3].x), Wc.w, a1);
        a2 = fmaf(__uint_as_float(u[cur][3].y << 16), Wc.w, a2);
        a3 = fmaf(__uint_as_float(u[cur][3].y), Wc.w, a3);
    }
    uint2 o;
    o.x = (unsigned)f2bu(a0) | ((unsigned)f2bu(a1) << 16);
    o.y = (unsigned)f2bu(a2) | ((unsigned)f2bu(a3) << 16);
    *(uint2*)(samp + (size_t)(q0 + qi) * 128 + h * 16 + c * 2) = o;
}

extern "C" void kernel_launch(void* const* d_in, const int* in_sizes, int n_in,
                              void* d_out, int out_size, void* d_ws, size_t ws_size,
                              hipStream_t stream) {
    const float* query  = (const float*)d_in[0];
    const float* refp   = (const float*)d_in[1];
    const float* inflat = (const float*)d_in[2];
    const float* Wq = (const float*)d_in[5];
    const float* bq = (const float*)d_in[6];
    const float* Wv = (const float*)d_in[7];
    const float* bv = (const float*)d_in[8];
    const float* Wa = (const float*)d_in[9];
    const float* ba = (const float*)d_in[10];
    const float* sloc = (const float*)d_in[11];
    const float* Wo = (const float*)d_in[12];
    const float* bo = (const float*)d_in[13];
    float* out = (float*)d_out;

    char* ws = (char*)d_ws;
    unsigned short* WqaT = (unsigned short*)(ws + 0);            // 64 KB  [128][256] bf16
    float* bqa = (float*)(ws + (64u << 10));                     // 512 B
    unsigned short* WvT = (unsigned short*)(ws + (128u << 10));  // 128 KB [256][256] bf16
    unsigned short* WoT = (unsigned short*)(ws + (256u << 10));  // 128 KB
    unsigned short* vbuf = (unsigned short*)(ws + (1u << 20));   // 22.3 MB bf16 [B][NTOK][256]
    float* logits = (float*)(ws + (24u << 20));                  // 8 MB fp32 [B*NQ][128]
    unsigned int* samp = (unsigned int*)(ws + (32u << 20));      // 8 MB bf16 [B*NQ][256]

    prep_kernel<<<384, 256, 0, stream>>>(Wq, Wa, bq, ba, Wv, Wo, WqaT, bqa, WvT, WoT);
    gemm_vlog<<<808, 256, 0, stream>>>(inflat, WvT, bv, vbuf, query, WqaT, bqa, logits);
    sample_kernel<<<BATCH * NQ / 4, 256, 0, stream>>>(refp, sloc, (const unsigned int*)vbuf, logits, samp);
    gemm_out<64, 128, 1, 4><<<dim3(2, 256), 256, 0, stream>>>((const unsigned short*)samp, WoT, bo, out, 256);
}